// Round 1
// baseline (552.016 us; speedup 1.0000x reference)
//
#include <hip/hip_runtime.h>

// NLSearch: B=1, T=4, C=64 (2 heads x 32), H=W=192, stride0=4 -> 48x48 queries,
// patch 7x7, offsets: dt in {-1,0,1}, di/dj in {-3..4} (L=192), top-K=7.
// Output: vals f32 [2][4*48*48][7] (129024) then inds-as-f32 [2][Q][7][3] (387072).

#define HH 192
#define WW 192

__device__ __forceinline__ int reflect_i(int idx, int n) {
    idx = idx < 0 ? -idx : idx;
    idx = idx >= n ? 2 * (n - 1) - idx : idx;
    return idx;
}

__global__ __launch_bounds__(256) void nls_kernel(
    const float* __restrict__ vid0,
    const float* __restrict__ vid1,
    float* __restrict__ out)
{
    // A: [c][y*7+x], stride 49 (odd -> conflict-free across c=lane)
    __shared__ float As[64 * 49];
    // B: [c][u*14+v], stride 197 (odd -> conflict-free across c=lane)
    __shared__ float Bs[64 * 197];
    __shared__ __align__(16) float score[2][192];

    const int blk = blockIdx.x;
    const int t   = blk / (48 * 48);
    const int rem = blk - t * (48 * 48);
    const int qi  = rem / 48;
    const int qj  = rem - qi * 48;
    const int qh  = qi * 4;
    const int qw  = qj * 4;

    const int tid  = threadIdx.x;
    const int lane = tid & 63;
    const int wid  = tid >> 6;  // 0..3

    // ---- stage A (vid0 patch) ----
    for (int idx = tid; idx < 64 * 49; idx += 256) {
        int cc = idx / 49;
        int p  = idx - cc * 49;
        int y  = p / 7;
        int x  = p - y * 7;
        int h  = reflect_i(qh + y - 3, HH);
        int w  = reflect_i(qw + x - 3, WW);
        As[idx] = vid0[((t * 64 + cc) * HH + h) * WW + w];
    }

    int tprev = -1;
    for (int dtI = 0; dtI < 3; ++dtI) {
        int tp = t + dtI - 1;
        tp = tp < 0 ? 0 : (tp > 3 ? 3 : tp);

        __syncthreads();  // protects Bs (prev compute done) + makes prev scores visible

        if (tp == tprev) {
            // clamp(t+dt) duplicate: copy scores bitwise -> exact ties, lower l wins
            if (tid < 128) {
                int head = tid >> 6;
                int o    = tid & 63;
                score[head][dtI * 64 + o] = score[head][(dtI - 1) * 64 + o];
            }
            continue;
        }
        tprev = tp;

        // ---- stage B region for this dt: rows u in [0,13] ~ qh-6..qh+7 ----
        if (tid < 196) {
            int u = tid / 14;
            int v = tid - u * 14;
            int h = reflect_i(qh + u - 6, HH);
            int w = reflect_i(qw + v - 6, WW);
            const float* src = vid1 + (((tp * 64) * HH + h) * WW + w);
            float* dst = &Bs[tid];
            #pragma unroll 16
            for (int cc = 0; cc < 64; ++cc) {
                dst[cc * 197] = src[cc * (HH * WW)];
            }
        }
        __syncthreads();

        // ---- compute: lane = channel, wave handles di rows {2*wid, 2*wid+1} ----
        {
            const float* Ac = &As[lane * 49];
            const float* Bc = &Bs[lane * 197 + (wid * 2) * 14];
            float acc[16];
            #pragma unroll
            for (int k = 0; k < 16; ++k) acc[k] = 0.f;

            float r0[14], r1[14];
            #pragma unroll
            for (int v = 0; v < 14; ++v) r0[v] = Bc[v];

            #pragma unroll
            for (int y = 0; y < 7; ++y) {
                #pragma unroll
                for (int v = 0; v < 14; ++v) r1[v] = Bc[(y + 1) * 14 + v];
                float a[7];
                #pragma unroll
                for (int x = 0; x < 7; ++x) a[x] = Ac[y * 7 + x];
                #pragma unroll
                for (int dj = 0; dj < 8; ++dj) {
                    #pragma unroll
                    for (int x = 0; x < 7; ++x) {
                        acc[dj]     = fmaf(a[x], r0[dj + x], acc[dj]);
                        acc[8 + dj] = fmaf(a[x], r1[dj + x], acc[8 + dj]);
                    }
                }
                #pragma unroll
                for (int v = 0; v < 14; ++v) r0[v] = r1[v];
            }

            // reduce over 32 channels per head (lanes 0-31 = head0, 32-63 = head1)
            #pragma unroll
            for (int k = 0; k < 16; ++k) {
                float v = acc[k];
                v += __shfl_xor(v, 1);
                v += __shfl_xor(v, 2);
                v += __shfl_xor(v, 4);
                v += __shfl_xor(v, 8);
                v += __shfl_xor(v, 16);
                acc[k] = v;
            }
            if ((lane & 31) == 0) {
                int head = lane >> 5;
                float* sp = &score[head][dtI * 64 + wid * 16];
                #pragma unroll
                for (int k = 0; k < 16; ++k) sp[k] = acc[k];
            }
        }
    }

    __syncthreads();

    // ---- top-K=7 over 192, per head; waves 0,1 only ----
    if (wid < 2) {
        int head = wid;
        float v0 = score[head][lane];
        float v1 = score[head][64 + lane];
        float v2 = score[head][128 + lane];
        int q     = (t * 48 + qi) * 48 + qj;
        int vbase = (head * 9216 + q) * 7;
        int ibase = 129024 + vbase * 3;
        for (int r = 0; r < 7; ++r) {
            // local argmax over l = {lane, lane+64, lane+128}; strict > keeps lower l
            float bv = v0; int bi = lane;
            if (v1 > bv) { bv = v1; bi = lane + 64; }
            if (v2 > bv) { bv = v2; bi = lane + 128; }
            // wave argmax, tie -> lower index (matches lax.top_k)
            #pragma unroll
            for (int m = 1; m <= 32; m <<= 1) {
                float ov = __shfl_xor(bv, m);
                int   oi = __shfl_xor(bi, m);
                if (ov > bv || (ov == bv && oi < bi)) { bv = ov; bi = oi; }
            }
            if (lane == 0) {
                out[vbase + r] = bv;
                int dtSel = bi >> 6;
                int r2    = bi & 63;
                int diSel = (r2 >> 3) - 3;
                int djSel = (r2 & 7) - 3;
                int ts = t + dtSel - 1;
                ts = ts < 0 ? 0 : (ts > 3 ? 3 : ts);
                int hs = reflect_i(qh + diSel, HH);
                int ws = reflect_i(qw + djSel, WW);
                float* op = out + ibase + 3 * r;
                op[0] = (float)ts;
                op[1] = (float)hs;
                op[2] = (float)ws;
            }
            // mask out the selected entry
            if ((bi & 63) == lane) {
                int slot = bi >> 6;
                if (slot == 0)      v0 = -3.4e38f;
                else if (slot == 1) v1 = -3.4e38f;
                else                v2 = -3.4e38f;
            }
        }
    }
}

extern "C" void kernel_launch(void* const* d_in, const int* in_sizes, int n_in,
                              void* d_out, int out_size, void* d_ws, size_t ws_size,
                              hipStream_t stream) {
    const float* vid0 = (const float*)d_in[0];
    const float* vid1 = (const float*)d_in[1];
    float* out = (float*)d_out;
    dim3 grid(4 * 48 * 48);
    dim3 block(256);
    hipLaunchKernelGGL(nls_kernel, grid, block, 0, stream, vid0, vid1, out);
}

// Round 2
// 517.462 us; speedup vs baseline: 1.0668x; 1.0668x over previous
//
#include <hip/hip_runtime.h>

// NLSearch: B=1, T=4, C=64 (2 heads x 32ch), H=W=192, stride0=4 -> 48x48 queries,
// patch 7x7, offsets dt{-1,0,1} x di,dj{-3..4} (L=192), top-K=7.
// Block = (head, t, qi, qj-pair): 2 heads x 4 t x 48 qi x 24 pairs = 9216 blocks.
// Out: vals f32 [2][9216][7] (129024) then inds [2][9216][7][3] (387072).

#define HH 192
#define WW 192
#define HW (HH * WW)

// LDS layout (floats):
//   Bs: [c 0..31][u 0..13][v 0..17 pad 20], c-stride 284 (mod 32 = 28 -> banks spread)
//   As: overlaid on Bs (consumed into regs before first B stage): [c][y 0..6][v 0..10 pad 12]
//   score: [2 queries][192]
#define BS_CSTR 284
#define BS_SZ   (32 * BS_CSTR)   // 9088
#define AS_CSTR 84

__device__ __forceinline__ int reflect_i(int idx, int n) {
    idx = idx < 0 ? -idx : idx;
    idx = idx >= n ? 2 * (n - 1) - idx : idx;
    return idx;
}

template <int CTRL>
__device__ __forceinline__ float dpp_add(float x) {
    int y = __builtin_amdgcn_update_dpp(0, __float_as_int(x), CTRL, 0xf, 0xf, true);
    return x + __int_as_float(y);
}

// lane31 <- sum(lanes 0..31), lane63 <- sum(lanes 32..63); VALU pipe (DPP), no LDS.
__device__ __forceinline__ float reduce32(float v) {
    v = dpp_add<0x111>(v);  // row_shr:1
    v = dpp_add<0x112>(v);  // row_shr:2
    v = dpp_add<0x114>(v);  // row_shr:4
    v = dpp_add<0x118>(v);  // row_shr:8  -> lane15=sum(0..15) per 16-row
    v = dpp_add<0x142>(v);  // row_bcast15 -> lane31=sum(0..31), lane63=sum(32..63)
    return v;
}

__global__ __launch_bounds__(256, 3) void nls_kernel(
    const float* __restrict__ vid0,
    const float* __restrict__ vid1,
    float* __restrict__ out)
{
    __shared__ float smem[BS_SZ + 2 * 192];
    float* Bs = smem;
    float* As = smem;             // overlaid; A consumed to regs before B staging
    float* score = smem + BS_SZ;  // [2][192]

    // XCD swizzle: xcd = blk&7 -> qi band of 6 rows; inner order (hd, t, qi_l, qjp)
    const int b    = blockIdx.x;
    const int xcd  = b & 7;
    const int loc  = b >> 3;          // 0..1151
    const int qjp  = loc % 24;
    const int r1   = loc / 24;        // 0..47
    const int qi_l = r1 % 6;
    const int r2   = r1 / 6;          // 0..7
    const int t    = r2 & 3;
    const int hd   = r2 >> 2;
    const int qi   = xcd * 6 + qi_l;

    const int qh  = qi * 4;
    const int qw0 = qjp * 8;          // query0 center col; query1 = qw0+4

    const int tid  = threadIdx.x;
    const int lane = tid & 63;
    const int wid  = tid >> 6;        // 0..3
    const int sc   = tid >> 3;        // staging channel 0..31
    const int vl   = tid & 7;

    // ---- stage A region: [32c][7u][11v] ----
    {
        const float* src = vid0 + (size_t)(t * 64 + hd * 32 + sc) * HW;
        const int wa0 = reflect_i(qw0 - 3 + vl, WW);
        const int wa1 = (vl < 3) ? reflect_i(qw0 - 3 + vl + 8, WW) : 0;
        float* dst = &As[sc * AS_CSTR + vl];
        #pragma unroll
        for (int u = 0; u < 7; ++u) {
            int hh = reflect_i(qh - 3 + u, HH);
            const float* rp = src + hh * WW;
            dst[u * 12] = rp[wa0];
            if (vl < 3) dst[u * 12 + 8] = rp[wa1];
        }
    }
    __syncthreads();

    // ---- A -> registers (dt-invariant). lane=c(0..31) x djhalf; wave=(q, dihalf) ----
    const int c     = lane & 31;
    const int hhalf = lane >> 5;      // dj-half: lanes 0-31 dj 0..3, 32-63 dj 4..7
    const int q     = wid >> 1;       // query within pair
    const int d     = wid & 1;        // di-half: rows 4d..4d+3

    float a[7][7];
    {
        const float* Ab = &As[c * AS_CSTR + 4 * q];
        #pragma unroll
        for (int y = 0; y < 7; ++y) {
            float4 lo = *(const float4*)(Ab + y * 12);
            float4 hi = *(const float4*)(Ab + y * 12 + 4);
            a[y][0] = lo.x; a[y][1] = lo.y; a[y][2] = lo.z; a[y][3] = lo.w;
            a[y][4] = hi.x; a[y][5] = hi.y; a[y][6] = hi.z;
        }
    }

    // B read base: window cols v0 = 4q + 4*hhalf (16B aligned), rows 4d + ...
    const float* Bc = &Bs[c * BS_CSTR + (4 * d) * 20 + 4 * q + 4 * hhalf];

    int tprev = -1;
    for (int dtI = 0; dtI < 3; ++dtI) {
        int tp = t + dtI - 1;
        tp = tp < 0 ? 0 : (tp > 3 ? 3 : tp);

        __syncthreads();  // prev compute done (Bs free), prev scores visible

        if (tp == tprev) {
            // clamp duplicate: bitwise copy -> exact ties, lower l wins
            if (tid < 128) {
                int qq = tid >> 6, o = tid & 63;
                score[qq * 192 + dtI * 64 + o] = score[qq * 192 + (dtI - 1) * 64 + o];
            }
            continue;
        }
        tprev = tp;

        // ---- stage B: [32c][14u][18v] ----
        {
            const float* src = vid1 + (size_t)(tp * 64 + hd * 32 + sc) * HW;
            const int w0 = reflect_i(qw0 - 6 + vl, WW);
            const int w1 = reflect_i(qw0 - 6 + vl + 8, WW);
            const int w2 = (vl < 2) ? reflect_i(qw0 - 6 + vl + 16, WW) : 0;
            float* dst = &Bs[sc * BS_CSTR + vl];
            #pragma unroll
            for (int u = 0; u < 14; ++u) {
                int hh2 = reflect_i(qh - 6 + u, HH);
                const float* rp = src + hh2 * WW;
                dst[u * 20]     = rp[w0];
                dst[u * 20 + 8] = rp[w1];
                if (vl < 2) dst[u * 20 + 16] = rp[w2];
            }
        }
        __syncthreads();

        // ---- compute: acc[di' 0..3][dj' 0..3], sliding 4-row x 12-float window ----
        {
            float acc[16];
            #pragma unroll
            for (int k = 0; k < 16; ++k) acc[k] = 0.f;

            float4 win[4][3];
            #pragma unroll
            for (int k = 0; k < 4; ++k) {
                #pragma unroll
                for (int j = 0; j < 3; ++j)
                    win[k][j] = *(const float4*)(Bc + k * 20 + j * 4);
            }

            #pragma unroll
            for (int y = 0; y < 7; ++y) {
                if (y > 0) {
                    const int slot = (y + 3) & 3;
                    #pragma unroll
                    for (int j = 0; j < 3; ++j)
                        win[slot][j] = *(const float4*)(Bc + (y + 3) * 20 + j * 4);
                }
                #pragma unroll
                for (int dip = 0; dip < 4; ++dip) {
                    const int s = (y + dip) & 3;
                    float bf[12];
                    bf[0] = win[s][0].x; bf[1] = win[s][0].y; bf[2]  = win[s][0].z; bf[3]  = win[s][0].w;
                    bf[4] = win[s][1].x; bf[5] = win[s][1].y; bf[6]  = win[s][1].z; bf[7]  = win[s][1].w;
                    bf[8] = win[s][2].x; bf[9] = win[s][2].y; bf[10] = win[s][2].z; bf[11] = win[s][2].w;
                    #pragma unroll
                    for (int djp = 0; djp < 4; ++djp) {
                        #pragma unroll
                        for (int x = 0; x < 7; ++x) {
                            acc[dip * 4 + djp] = fmaf(a[y][x], bf[djp + x], acc[dip * 4 + djp]);
                        }
                    }
                }
            }

            // channel reduction on VALU (DPP); lane31 -> dj-half0, lane63 -> dj-half1
            #pragma unroll
            for (int k = 0; k < 16; ++k) acc[k] = reduce32(acc[k]);

            if ((lane & 31) == 31) {
                float* sp = &score[q * 192 + dtI * 64 + 4 * hhalf];
                #pragma unroll
                for (int dip = 0; dip < 4; ++dip) {
                    float4 v4 = make_float4(acc[dip * 4 + 0], acc[dip * 4 + 1],
                                            acc[dip * 4 + 2], acc[dip * 4 + 3]);
                    *(float4*)(sp + (4 * d + dip) * 8) = v4;
                }
            }
        }
    }

    __syncthreads();

    // ---- top-K=7 over 192 per query; waves 0,1 (one per query) ----
    if (wid < 2) {
        const int qq = wid;
        const int qj = 2 * qjp + qq;
        float v0 = score[qq * 192 + lane];
        float v1 = score[qq * 192 + 64 + lane];
        float v2 = score[qq * 192 + 128 + lane];
        const int qglob = (t * 48 + qi) * 48 + qj;
        const int vbase = (hd * 9216 + qglob) * 7;
        const int ibase = 129024 + vbase * 3;
        for (int r = 0; r < 7; ++r) {
            float bv = v0; int bi = lane;
            if (v1 > bv) { bv = v1; bi = lane + 64; }
            if (v2 > bv) { bv = v2; bi = lane + 128; }
            #pragma unroll
            for (int m = 1; m <= 32; m <<= 1) {
                float ov = __shfl_xor(bv, m);
                int   oi = __shfl_xor(bi, m);
                if (ov > bv || (ov == bv && oi < bi)) { bv = ov; bi = oi; }
            }
            if (lane == 0) {
                out[vbase + r] = bv;
                int dtSel = bi >> 6;
                int rr    = bi & 63;
                int diSel = (rr >> 3) - 3;
                int djSel = (rr & 7) - 3;
                int ts = t + dtSel - 1;
                ts = ts < 0 ? 0 : (ts > 3 ? 3 : ts);
                int hs = reflect_i(qh + diSel, HH);
                int ws = reflect_i(qj * 4 + djSel, WW);
                float* op = out + ibase + 3 * r;
                op[0] = (float)ts;
                op[1] = (float)hs;
                op[2] = (float)ws;
            }
            if ((bi & 63) == lane) {
                int slot = bi >> 6;
                if (slot == 0)      v0 = -3.4e38f;
                else if (slot == 1) v1 = -3.4e38f;
                else                v2 = -3.4e38f;
            }
        }
    }
}

extern "C" void kernel_launch(void* const* d_in, const int* in_sizes, int n_in,
                              void* d_out, int out_size, void* d_ws, size_t ws_size,
                              hipStream_t stream) {
    const float* vid0 = (const float*)d_in[0];
    const float* vid1 = (const float*)d_in[1];
    float* out = (float*)d_out;
    dim3 grid(9216);
    dim3 block(256);
    hipLaunchKernelGGL(nls_kernel, grid, block, 0, stream, vid0, vid1, out);
}